// Round 1
// baseline (18576.590 us; speedup 1.0000x reference)
//
#include <hip/hip_runtime.h>
#include <math.h>

#define N_NODES 10000
#define IN_DIM  256
#define HID     512
#define NH      4
#define HDIM    128
#define DEG     16
#define KNN_K   15
#define QDIM    32
#define EB      64
#define EIG_ITERS 72
#define JAC_SWEEPS 10
#define SLOPE   0.2f

// ---------------------------------------------------------------- fp32 GEMM
// C[n x m] = act(A[n x k] @ B[k x m] + bias);  m%64==0, k%16==0, n guarded
__global__ __launch_bounds__(256) void gemm_kernel(
    const float* __restrict__ A, const float* __restrict__ B,
    const float* __restrict__ bias, float* __restrict__ C,
    int n, int k, int m, int act) {
  __shared__ float As[16][68];
  __shared__ float Bs[16][68];
  int tid = threadIdx.x;
  int tx = tid % 16, ty = tid / 16;
  int r0 = blockIdx.y * 64, c0 = blockIdx.x * 64;
  float acc[4][4] = {};
  for (int k0 = 0; k0 < k; k0 += 16) {
    {
      int row = tid / 4;            // 0..63
      int kc  = (tid % 4) * 4;      // 0..12
      int gr = r0 + row;
      float4 v = make_float4(0.f, 0.f, 0.f, 0.f);
      if (gr < n) v = *(const float4*)(A + (size_t)gr * k + k0 + kc);
      As[kc + 0][row] = v.x; As[kc + 1][row] = v.y;
      As[kc + 2][row] = v.z; As[kc + 3][row] = v.w;
      int kr = tid / 16;            // 0..15
      int cc = (tid % 16) * 4;      // 0..60
      float4 w = *(const float4*)(B + (size_t)(k0 + kr) * m + c0 + cc);
      *(float4*)&Bs[kr][cc] = w;
    }
    __syncthreads();
#pragma unroll
    for (int kk = 0; kk < 16; kk++) {
      float a[4], b[4];
#pragma unroll
      for (int i = 0; i < 4; i++) a[i] = As[kk][ty * 4 + i];
#pragma unroll
      for (int j = 0; j < 4; j++) b[j] = Bs[kk][tx * 4 + j];
#pragma unroll
      for (int i = 0; i < 4; i++)
#pragma unroll
        for (int j = 0; j < 4; j++) acc[i][j] += a[i] * b[j];
    }
    __syncthreads();
  }
  for (int i = 0; i < 4; i++) {
    int gr = r0 + ty * 4 + i;
    if (gr >= n) break;
    for (int j = 0; j < 4; j++) {
      int gc = c0 + tx * 4 + j;
      float v = acc[i][j] + (bias ? bias[gc] : 0.f);
      if (act == 1) v = fmaxf(v, 0.f);
      C[(size_t)gr * m + gc] = v;
    }
  }
}

// ---------------------------------------------------------------- eigen path
__global__ void zerod_kernel(double* p, int n) {
  int i = blockIdx.x * 256 + threadIdx.x;
  if (i < n) p[i] = 0.0;
}

__global__ void colmean_kernel(const float* __restrict__ h, double* __restrict__ mu) {
  int r0 = blockIdx.x * 64;
  int t = threadIdx.x;
  double s0 = 0, s1 = 0;
  for (int i = 0; i < 64; i++) {
    int r = r0 + i;
    if (r >= N_NODES) break;
    s0 += (double)h[(size_t)r * HID + t];
    s1 += (double)h[(size_t)r * HID + t + 256];
  }
  atomicAdd(&mu[t], s0);
  atomicAdd(&mu[t + 256], s1);
}

// C[i][j] = sum_n (h[n][i]-mu_i)(h[n][j]-mu_j), fp64.  grid (16,16), 32x32 tile
__global__ void gram_kernel(const float* __restrict__ h, const double* __restrict__ mu,
                            double* __restrict__ C) {
  __shared__ double Ai[64][33];
  __shared__ double Aj[64][33];
  int i0 = blockIdx.y * 32, j0 = blockIdx.x * 32;
  int tid = threadIdx.x;
  int tx = tid % 16, ty = tid / 16;
  double acc[2][2] = {};
  const double invN = 1.0 / (double)N_NODES;
  for (int n0 = 0; n0 < N_NODES; n0 += 64) {
    for (int e = tid; e < 64 * 32; e += 256) {
      int rr = e / 32, cc = e % 32;
      int gn = n0 + rr;
      double vi = 0, vj = 0;
      if (gn < N_NODES) {
        vi = (double)h[(size_t)gn * HID + i0 + cc] - mu[i0 + cc] * invN;
        vj = (double)h[(size_t)gn * HID + j0 + cc] - mu[j0 + cc] * invN;
      }
      Ai[rr][cc] = vi; Aj[rr][cc] = vj;
    }
    __syncthreads();
    int nmax = min(64, N_NODES - n0);
    for (int nn = 0; nn < nmax; nn++) {
      double ai0 = Ai[nn][ty * 2], ai1 = Ai[nn][ty * 2 + 1];
      double aj0 = Aj[nn][tx * 2], aj1 = Aj[nn][tx * 2 + 1];
      acc[0][0] += ai0 * aj0; acc[0][1] += ai0 * aj1;
      acc[1][0] += ai1 * aj0; acc[1][1] += ai1 * aj1;
    }
    __syncthreads();
  }
  for (int a = 0; a < 2; a++)
    for (int b = 0; b < 2; b++)
      C[(size_t)(i0 + ty * 2 + a) * HID + j0 + tx * 2 + b] = acc[a][b];
}

// fp64 GEMM C[n x m] = A[n x k] @ B[k x m]; all dims %32==0 here (or m=64)
__global__ void dgemm_kernel(const double* __restrict__ A, const double* __restrict__ B,
                             double* __restrict__ C, int n, int k, int m) {
  __shared__ double As[16][34];
  __shared__ double Bs[16][34];
  int tid = threadIdx.x;
  int tx = tid % 16, ty = tid / 16;
  int r0 = blockIdx.y * 32, c0 = blockIdx.x * 32;
  double acc[2][2] = {};
  for (int k0 = 0; k0 < k; k0 += 16) {
    for (int e = tid; e < 32 * 16; e += 256) {
      int rr = e / 16, kk = e % 16;
      As[kk][rr] = A[(size_t)(r0 + rr) * k + k0 + kk];
    }
    for (int e = tid; e < 16 * 32; e += 256) {
      int kk = e / 32, cc = e % 32;
      Bs[kk][cc] = B[(size_t)(k0 + kk) * m + c0 + cc];
    }
    __syncthreads();
#pragma unroll
    for (int kk = 0; kk < 16; kk++) {
      double a0 = As[kk][ty * 2], a1 = As[kk][ty * 2 + 1];
      double b0 = Bs[kk][tx * 2], b1 = Bs[kk][tx * 2 + 1];
      acc[0][0] += a0 * b0; acc[0][1] += a0 * b1;
      acc[1][0] += a1 * b0; acc[1][1] += a1 * b1;
    }
    __syncthreads();
  }
  C[(size_t)(r0 + ty * 2) * m + c0 + tx * 2]         = acc[0][0];
  C[(size_t)(r0 + ty * 2) * m + c0 + tx * 2 + 1]     = acc[0][1];
  C[(size_t)(r0 + ty * 2 + 1) * m + c0 + tx * 2]     = acc[1][0];
  C[(size_t)(r0 + ty * 2 + 1) * m + c0 + tx * 2 + 1] = acc[1][1];
}

__global__ void initx_kernel(double* X) {
  int i = blockIdx.x * 256 + threadIdx.x;
  if (i < HID * EB) {
    unsigned u = (unsigned)i * 2654435761u + 12345u;
    u ^= u >> 16; u *= 2246822519u; u ^= u >> 13; u *= 3266489917u; u ^= u >> 16;
    X[i] = (double)(u & 0xFFFFFF) / (double)0x1000000 - 0.5;
  }
}

// T = A^T B  for A,B [512 x 64]; grid 64 blocks (one output row each)
__global__ void atb_kernel(const double* __restrict__ A, const double* __restrict__ B,
                           double* __restrict__ T) {
  __shared__ double part[4][64];
  int r = blockIdx.x;
  int j = threadIdx.x % 64;
  int ch = threadIdx.x / 64;
  double s = 0;
  for (int kk = ch * 128; kk < ch * 128 + 128; kk++)
    s += A[kk * EB + r] * B[kk * EB + j];
  part[ch][j] = s;
  __syncthreads();
  if (threadIdx.x < 64)
    T[r * EB + j] = part[0][j] + part[1][j] + part[2][j] + part[3][j];
}

// CholQR apply: chol(G) redundantly per block, then X(rows of this block) = Y R^-1
__global__ __launch_bounds__(256) void cholsolve_kernel(
    const double* __restrict__ G, const double* __restrict__ Y, double* __restrict__ X) {
  __shared__ double M[64][65];
  __shared__ double dmax_sh;
  int t = threadIdx.x;
  for (int e = t; e < 64 * 64; e += 256) M[e / 64][e % 64] = G[e];
  __syncthreads();
  if (t == 0) {
    double dm = 1e-300;
    for (int j = 0; j < 64; j++) dm = fmax(dm, M[j][j]);
    dmax_sh = dm;
  }
  __syncthreads();
  double dmax = dmax_sh;
  for (int kc = 0; kc < 64; kc++) {
    if (t < 64 && t >= kc) {
      double piv = fmax(M[kc][kc], dmax * 1e-28);
      double pr = sqrt(piv);
      M[t][kc] = (t == kc) ? pr : M[t][kc] / pr;
    }
    __syncthreads();
    if (t < 64 && t > kc) {
      double lr = M[t][kc];
      for (int c = kc + 1; c <= t; c++) M[t][c] -= lr * M[c][kc];
    }
    __syncthreads();
  }
  int row = blockIdx.x * 256 + t;
  double x[64];
#pragma unroll
  for (int j = 0; j < 64; j++) x[j] = Y[row * 64 + j];
#pragma unroll
  for (int j = 0; j < 64; j++) {
    double s = x[j];
#pragma unroll
    for (int i = 0; i < j; i++) s -= x[i] * M[j][i];
    x[j] = s / M[j][j];
  }
#pragma unroll
  for (int j = 0; j < 64; j++) X[row * 64 + j] = x[j];
}

// parallel-ordered cyclic Jacobi on 64x64 symmetric T (double, LDS);
// U accumulated in GLOBAL, column-major double.  sel = indices of top-32 eigvals.
__global__ __launch_bounds__(256) void jacobi_kernel(
    const double* __restrict__ Tin, double* __restrict__ Ucm, int* __restrict__ sel) {
  __shared__ double Td[64][65];
  __shared__ double cs[32], sn[32];
  __shared__ int pp[32], pq[32];
  int t = threadIdx.x;
  for (int e = t; e < 64 * 64; e += 256) {
    int r = e / 64, c = e % 64;
    Td[r][c] = 0.5 * (Tin[r * 64 + c] + Tin[c * 64 + r]);
    Ucm[e] = ((e / 64) == (e % 64)) ? 1.0 : 0.0;  // column-major identity
  }
  __syncthreads();
  for (int sweep = 0; sweep < JAC_SWEEPS; sweep++) {
    for (int round = 0; round < 63; round++) {
      if (t < 32) {
        int a = (t == 0) ? 0 : ((t - 1 + round) % 63) + 1;
        int b = ((62 - t + round) % 63) + 1;
        int p = min(a, b), q = max(a, b);
        pp[t] = p; pq[t] = q;
        double app = Td[p][p], aqq = Td[q][q], apq = Td[p][q];
        double c_ = 1.0, s_ = 0.0;
        double scale = fabs(app) + fabs(aqq);
        if (apq != 0.0 && fabs(apq) > scale * 1e-17) {
          double tau = (aqq - app) / (2.0 * apq);
          double tt = (tau >= 0 ? 1.0 : -1.0) / (fabs(tau) + sqrt(1.0 + tau * tau));
          c_ = 1.0 / sqrt(1.0 + tt * tt);
          s_ = tt * c_;
        }
        cs[t] = c_; sn[t] = s_;
      }
      __syncthreads();
      for (int e = t; e < 2048; e += 256) {  // row phase
        int pi = e >> 6, k = e & 63;
        int p = pp[pi], q = pq[pi];
        double c_ = cs[pi], s_ = sn[pi];
        double tp = Td[p][k], tq = Td[q][k];
        Td[p][k] = c_ * tp - s_ * tq;
        Td[q][k] = s_ * tp + c_ * tq;
      }
      __syncthreads();
      for (int e = t; e < 2048; e += 256) {  // col phase + U
        int pi = e >> 6, k = e & 63;
        int p = pp[pi], q = pq[pi];
        double c_ = cs[pi], s_ = sn[pi];
        double tp = Td[k][p], tq = Td[k][q];
        Td[k][p] = c_ * tp - s_ * tq;
        Td[k][q] = s_ * tp + c_ * tq;
        double up = Ucm[p * 64 + k], uq = Ucm[q * 64 + k];
        Ucm[p * 64 + k] = c_ * up - s_ * uq;
        Ucm[q * 64 + k] = s_ * up + c_ * uq;
      }
      __syncthreads();
    }
  }
  if (t == 0) {
    double vals[64]; int idx[64];
    for (int j = 0; j < 64; j++) { vals[j] = Td[j][j]; idx[j] = j; }
    for (int r = 0; r < 32; r++) {
      int best = r;
      for (int j = r + 1; j < 64; j++) if (vals[j] > vals[best]) best = j;
      double tv = vals[r]; vals[r] = vals[best]; vals[best] = tv;
      int ti = idx[r]; idx[r] = idx[best]; idx[best] = ti;
      sel[r] = idx[r];
    }
  }
}

// V[512 x 32] = X[512 x 64] @ U[:, sel]   (U column-major)
__global__ void vmat_kernel(const double* __restrict__ X, const double* __restrict__ Ucm,
                            const int* __restrict__ sel, double* __restrict__ V) {
  int gid = blockIdx.x * 256 + threadIdx.x;
  int r = gid / QDIM, c = gid % QDIM;
  int uc = sel[c];
  double s = 0;
  for (int k = 0; k < 64; k++) s += X[r * 64 + k] * Ucm[uc * 64 + k];
  V[r * QDIM + c] = s;
}

// loc = h @ V (fp64).  grid 1250, 8 rows x 32 cols per block
__global__ void loc_kernel(const float* __restrict__ h, const double* __restrict__ V,
                           double* __restrict__ loc) {
  __shared__ float hs[8][HID];
  int r0 = blockIdx.x * 8;
  int tid = threadIdx.x;
  for (int e = tid; e < 8 * HID; e += 256) {
    int rr = e / HID, c = e % HID;
    int gr = r0 + rr;
    hs[rr][c] = (gr < N_NODES) ? h[(size_t)gr * HID + c] : 0.f;
  }
  __syncthreads();
  int rr = tid / 32, q = tid % 32;
  double s = 0;
  for (int k = 0; k < HID; k++) s += (double)hs[rr][k] * V[k * QDIM + q];
  int gr = r0 + rr;
  if (gr < N_NODES) loc[(size_t)gr * QDIM + q] = s;
}

__global__ void sq_kernel(const double* __restrict__ loc, double* __restrict__ sq) {
  int n = blockIdx.x * 256 + threadIdx.x;
  if (n < N_NODES) {
    double s = 0;
    for (int q = 0; q < QDIM; q++) { double v = loc[(size_t)n * QDIM + q]; s += v * v; }
    sq[n] = s;
  }
}

__device__ __forceinline__ bool lexless(double d1, int i1, double d2, int i2) {
  return (d1 < d2) || (d1 == d2 && i1 < i2);
}

// KNN: 16 nodes per block, 16 lanes per node; fp64 distances; ties -> lower idx
__global__ __launch_bounds__(256) void knn_kernel(
    const double* __restrict__ loc, const double* __restrict__ sq, int* __restrict__ knn) {
  __shared__ double smem_d[5760];
  double* li  = smem_d;            // 16*32
  double* lj  = smem_d + 512;      // 64*33 padded
  double* sqj = smem_d + 512 + 2112;  // 64
  int tid = threadIdx.x;
  int i_loc = tid / 16, lane = tid % 16;
  int i0 = blockIdx.x * 16;
  for (int e = tid; e < 16 * 32; e += 256)
    li[e] = loc[(size_t)(i0 + e / 32) * QDIM + (e % 32)];
  __syncthreads();
  double sqi = sq[i0 + i_loc];
  double bd[15]; int bi[15];
#pragma unroll
  for (int r = 0; r < 15; r++) { bd[r] = 1e300; bi[r] = 0x7fffffff; }

  for (int j0 = 0; j0 < N_NODES; j0 += 64) {
    int jcount = min(64, N_NODES - j0);
    __syncthreads();
    for (int e = tid; e < 64 * 32; e += 256) {
      int jj = e / 32, q = e % 32;
      if (j0 + jj < N_NODES) lj[jj * 33 + q] = loc[(size_t)(j0 + jj) * QDIM + q];
    }
    for (int e = tid; e < 64; e += 256) { }
    if (tid < 64 && j0 + tid < N_NODES) sqj[tid] = sq[j0 + tid];
    __syncthreads();
    for (int jj = lane; jj < jcount; jj += 16) {
      double dot = 0;
#pragma unroll
      for (int q = 0; q < 32; q++) dot += li[i_loc * 32 + q] * lj[jj * 33 + q];
      double dj = sqi + sqj[jj] - 2.0 * dot;
      int gj = j0 + jj;
      if (lexless(dj, gj, bd[14], bi[14])) {
        bool placed = false;
#pragma unroll
        for (int r = 14; r > 0; r--) {
          if (!placed) {
            if (lexless(bd[r - 1], bi[r - 1], dj, gj)) {
              bd[r] = dj; bi[r] = gj; placed = true;
            } else {
              bd[r] = bd[r - 1]; bi[r] = bi[r - 1];
            }
          }
        }
        if (!placed) { bd[0] = dj; bi[0] = gj; }
      }
    }
  }
  __syncthreads();
  // merge: overlay LDS
  double* mdist = smem_d;                 // 3840
  int* midx = (int*)(smem_d + 3840);      // 3840
  int base = (i_loc * 16 + lane) * 15;
  for (int r = 0; r < 15; r++) { mdist[base + r] = bd[r]; midx[base + r] = bi[r]; }
  __syncthreads();
  if (lane == 0) {
    int ptr[16];
    for (int l2 = 0; l2 < 16; l2++) ptr[l2] = 0;
    for (int r = 0; r < 15; r++) {
      double best = 1e301; int bidx = 0x7fffffff; int bl = 0;
      for (int l2 = 0; l2 < 16; l2++) {
        if (ptr[l2] < 15) {
          double dv = mdist[(i_loc * 16 + l2) * 15 + ptr[l2]];
          int iv = midx[(i_loc * 16 + l2) * 15 + ptr[l2]];
          if (lexless(dv, iv, best, bidx)) { best = dv; bidx = iv; bl = l2; }
        }
      }
      ptr[bl]++;
      knn[(size_t)(i0 + i_loc) * KNN_K + r] = bidx;
    }
  }
}

// ---------------------------------------------------------------- GAT kernels
// GATv2: one block per node v (256 threads, channels t and t+256)
__global__ __launch_bounds__(256) void gatv2_kernel(
    const float* __restrict__ fs, const float* __restrict__ fd,
    const int* __restrict__ src, const float* __restrict__ attn,
    float* __restrict__ out) {
  __shared__ float part1[DEG][4], part2[DEG][4];
  __shared__ float scores[DEG][NH];
  __shared__ float aw[DEG][NH];
  int v = blockIdx.x, t = threadIdx.x;
  int wave = t / 64, lane = t % 64;
  float rfd0 = fd[(size_t)v * HID + t];
  float rfd1 = fd[(size_t)v * HID + t + 256];
  float at0 = attn[t], at1 = attn[t + 256];
  float afs0[DEG], afs1[DEG];
#pragma unroll
  for (int d = 0; d < DEG; d++) {
    int u = src[(size_t)v * DEG + d];
    float f0 = fs[(size_t)u * HID + t];
    float f1 = fs[(size_t)u * HID + t + 256];
    afs0[d] = f0; afs1[d] = f1;
    float e0 = f0 + rfd0; e0 = e0 > 0.f ? e0 : SLOPE * e0;
    float e1 = f1 + rfd1; e1 = e1 > 0.f ? e1 : SLOPE * e1;
    float v0 = e0 * at0, v1 = e1 * at1;
    for (int off = 32; off; off >>= 1) {
      v0 += __shfl_down(v0, off, 64);
      v1 += __shfl_down(v1, off, 64);
    }
    if (lane == 0) { part1[d][wave] = v0; part2[d][wave] = v1; }
  }
  __syncthreads();
  if (t < DEG * NH) {
    int d = t / NH, hh = t % NH;
    float s;
    if (hh < 2) s = part1[d][hh * 2] + part1[d][hh * 2 + 1];
    else        s = part2[d][(hh - 2) * 2] + part2[d][(hh - 2) * 2 + 1];
    scores[d][hh] = s;
  }
  __syncthreads();
  if (t < NH) {
    float m = -1e30f;
    for (int d = 0; d < DEG; d++) m = fmaxf(m, scores[d][t]);
    float ss = 0.f;
    for (int d = 0; d < DEG; d++) { float e_ = expf(scores[d][t] - m); aw[d][t] = e_; ss += e_; }
    float inv = 1.f / ss;
    for (int d = 0; d < DEG; d++) aw[d][t] *= inv;
  }
  __syncthreads();
  int h0 = t / HDIM, h1 = (t + 256) / HDIM;
  float o0 = 0.f, o1 = 0.f;
#pragma unroll
  for (int d = 0; d < DEG; d++) { o0 += aw[d][h0] * afs0[d]; o1 += aw[d][h1] * afs1[d]; }
  out[(size_t)v * HID + t] = o0;
  out[(size_t)v * HID + t + 256] = o1;
}

// el/er for GATConv: per node, attn-dotted projections
__global__ __launch_bounds__(256) void elr_kernel(
    const float* __restrict__ f, const float* __restrict__ al, const float* __restrict__ ar,
    float* __restrict__ el, float* __restrict__ er) {
  __shared__ float pl[4][2], pr_[4][2];
  int v = blockIdx.x, t = threadIdx.x;
  int wave = t / 64, lane = t % 64;
  float f0 = f[(size_t)v * HID + t], f1 = f[(size_t)v * HID + t + 256];
  float l0 = f0 * al[t], l1 = f1 * al[t + 256];
  float r0 = f0 * ar[t], r1 = f1 * ar[t + 256];
  for (int off = 32; off; off >>= 1) {
    l0 += __shfl_down(l0, off, 64); l1 += __shfl_down(l1, off, 64);
    r0 += __shfl_down(r0, off, 64); r1 += __shfl_down(r1, off, 64);
  }
  if (lane == 0) { pl[wave][0] = l0; pl[wave][1] = l1; pr_[wave][0] = r0; pr_[wave][1] = r1; }
  __syncthreads();
  if (t < NH) {
    float ev, rv;
    if (t < 2) { ev = pl[t * 2][0] + pl[t * 2 + 1][0]; rv = pr_[t * 2][0] + pr_[t * 2 + 1][0]; }
    else { ev = pl[(t - 2) * 2][1] + pl[(t - 2) * 2 + 1][1]; rv = pr_[(t - 2) * 2][1] + pr_[(t - 2) * 2 + 1][1]; }
    el[(size_t)v * NH + t] = ev;
    er[(size_t)v * NH + t] = rv;
  }
}

__global__ __launch_bounds__(256) void gat_agg_kernel(
    const float* __restrict__ f, const int* __restrict__ knn,
    const float* __restrict__ el, const float* __restrict__ er,
    const float* __restrict__ bias, float* __restrict__ out) {
  __shared__ float aw[KNN_K][NH];
  __shared__ int us[KNN_K];
  int v = blockIdx.x, t = threadIdx.x;
  if (t < KNN_K) us[t] = knn[(size_t)v * KNN_K + t];
  __syncthreads();
  if (t < KNN_K * NH) {
    int d = t / NH, hh = t % NH;
    float s = el[(size_t)us[d] * NH + hh] + er[(size_t)v * NH + hh];
    s = s > 0.f ? s : SLOPE * s;
    aw[d][hh] = s;
  }
  __syncthreads();
  if (t < NH) {
    float m = -1e30f;
    for (int d = 0; d < KNN_K; d++) m = fmaxf(m, aw[d][t]);
    float ss = 0.f;
    for (int d = 0; d < KNN_K; d++) { float e_ = expf(aw[d][t] - m); aw[d][t] = e_; ss += e_; }
    float inv = 1.f / ss;
    for (int d = 0; d < KNN_K; d++) aw[d][t] *= inv;
  }
  __syncthreads();
  int h0 = t / HDIM, h1 = (t + 256) / HDIM;
  float o0 = bias[t], o1 = bias[t + 256];
#pragma unroll
  for (int d = 0; d < KNN_K; d++) {
    const float* fr = f + (size_t)us[d] * HID;
    o0 += aw[d][h0] * fr[t];
    o1 += aw[d][h1] * fr[t + 256];
  }
  out[(size_t)v * HID + t] = o0;
  out[(size_t)v * HID + t + 256] = o1;
}

__global__ __launch_bounds__(256) void gate_kernel(
    const float* __restrict__ h0b, const float* __restrict__ gw,
    const float* __restrict__ gb, float* __restrict__ theta) {
  __shared__ float p[4][2];
  int v = blockIdx.x, t = threadIdx.x;
  int wave = t / 64, lane = t % 64;
  float a0 = h0b[(size_t)v * HID + t], a1 = h0b[(size_t)v * HID + t + 256];
  float s0 = a0 * gw[t * 2 + 0] + a1 * gw[(t + 256) * 2 + 0];
  float s1 = a0 * gw[t * 2 + 1] + a1 * gw[(t + 256) * 2 + 1];
  for (int off = 32; off; off >>= 1) {
    s0 += __shfl_down(s0, off, 64);
    s1 += __shfl_down(s1, off, 64);
  }
  if (lane == 0) { p[wave][0] = s0; p[wave][1] = s1; }
  __syncthreads();
  if (t == 0) {
    float x0 = p[0][0] + p[1][0] + p[2][0] + p[3][0] + gb[0];
    float x1 = p[0][1] + p[1][1] + p[2][1] + p[3][1] + gb[1];
    float m = fmaxf(x0, x1);
    float e0 = expf(x0 - m), e1 = expf(x1 - m);
    float inv = 1.f / (e0 + e1);
    theta[v * 2 + 0] = e0 * inv;
    theta[v * 2 + 1] = e1 * inv;
  }
}

__global__ void combine0_kernel(const float* __restrict__ h0b, const float* __restrict__ h1b,
                                float* __restrict__ hout) {
  size_t i = (size_t)blockIdx.x * 256 + threadIdx.x;
  if (i < (size_t)N_NODES * HID) hout[i] = fmaxf(h0b[i] + h1b[i], 0.f);
}

__global__ void combine1_kernel(const float* __restrict__ h0b, const float* __restrict__ h1b,
                                const float* __restrict__ h2b, const float* __restrict__ theta,
                                float* __restrict__ out) {
  size_t i = (size_t)blockIdx.x * 256 + threadIdx.x;
  if (i < (size_t)N_NODES * HID) {
    int v = (int)(i / HID);
    float val = h0b[i] + theta[v * 2] * h1b[i] + theta[v * 2 + 1] * h2b[i];
    out[i] = fmaxf(val, 0.f);
  }
}

// ---------------------------------------------------------------- launch
extern "C" void kernel_launch(void* const* d_in, const int* in_sizes, int n_in,
                              void* d_out, int out_size, void* d_ws, size_t ws_size,
                              hipStream_t stream) {
  const float* inputs  = (const float*)d_in[0];
  const int*   src_idx = (const int*)d_in[1];
  const float* emb_w   = (const float*)d_in[2];
  const float* emb_b   = (const float*)d_in[3];
  const float* w3      = (const float*)d_in[4];
  const float* b3      = (const float*)d_in[5];
  const float* v2_wsrc = (const float*)d_in[6];
  const float* v2_bsrc = (const float*)d_in[7];
  const float* v2_wdst = (const float*)d_in[8];
  const float* v2_bdst = (const float*)d_in[9];
  const float* v2_attn = (const float*)d_in[10];
  const float* gat_w   = (const float*)d_in[11];
  const float* gat_al  = (const float*)d_in[12];
  const float* gat_ar  = (const float*)d_in[13];
  const float* gat_bias= (const float*)d_in[14];
  const float* gate_w  = (const float*)d_in[15];
  const float* gate_b  = (const float*)d_in[16];
  float* out = (float*)d_out;

  const size_t NE = (size_t)N_NODES * HID;  // 5,120,000
  float* h    = (float*)d_ws;
  float* h0b  = h + NE;
  float* h1b  = h0b + NE;
  float* h2b  = h1b + NE;
  float* fsb  = h2b + NE;
  float* fdb  = fsb + NE;
  float* theta= fdb + NE;          // 20000
  float* el   = theta + 20000;     // 40000
  float* er   = el + 40000;        // 40000
  double* mu  = (double*)(er + 40000);   // byte offset 123,280,000 (16B aligned)
  double* C   = mu + 512;
  double* C2  = C + 262144;
  double* C4  = C2 + 262144;
  double* X   = C4 + 262144;       // 512*64
  double* Y   = X + 32768;
  double* G   = Y + 32768;         // 64*64
  double* T   = G + 4096;
  double* Ucm = T + 4096;
  double* V   = Ucm + 4096;        // 512*32
  double* loc = V + 16384;         // 10000*32
  double* sq  = loc + 320000;
  int* sel    = (int*)(sq + 10000);
  int* knn    = sel + 32;          // 150000 ints

  dim3 gemm_grid(HID / 64, (N_NODES + 63) / 64);  // (8,157)

  // ---- embedding
  gemm_kernel<<<gemm_grid, 256, 0, stream>>>(inputs, emb_w, emb_b, h, N_NODES, IN_DIM, HID, 1);

  // ---- layer 0 (SVD/KNN/GAT/gate are dead code for l==0)
  gemm_kernel<<<gemm_grid, 256, 0, stream>>>(h, w3, b3, h0b, N_NODES, HID, HID, 0);
  gemm_kernel<<<gemm_grid, 256, 0, stream>>>(h, v2_wsrc, v2_bsrc, fsb, N_NODES, HID, HID, 0);
  gemm_kernel<<<gemm_grid, 256, 0, stream>>>(h, v2_wdst, v2_bdst, fdb, N_NODES, HID, HID, 0);
  gatv2_kernel<<<N_NODES, 256, 0, stream>>>(fsb, fdb, src_idx, v2_attn, h1b);
  combine0_kernel<<<(int)((NE + 255) / 256), 256, 0, stream>>>(h0b, h1b, h);

  // ---- layer 1: eigen-subspace of centered Gram (fp64)
  zerod_kernel<<<2, 256, 0, stream>>>(mu, 512);
  colmean_kernel<<<157, 256, 0, stream>>>(h, mu);
  gram_kernel<<<dim3(16, 16), 256, 0, stream>>>(h, mu, C);
  dgemm_kernel<<<dim3(16, 16), 256, 0, stream>>>(C, C, C2, HID, HID, HID);
  dgemm_kernel<<<dim3(16, 16), 256, 0, stream>>>(C2, C2, C4, HID, HID, HID);
  initx_kernel<<<128, 256, 0, stream>>>(X);
  for (int it = 0; it < EIG_ITERS; it++) {
    dgemm_kernel<<<dim3(2, 16), 256, 0, stream>>>(C4, X, Y, HID, HID, EB);
    atb_kernel<<<64, 256, 0, stream>>>(Y, Y, G);
    cholsolve_kernel<<<2, 256, 0, stream>>>(G, Y, X);
  }
  dgemm_kernel<<<dim3(2, 16), 256, 0, stream>>>(C4, X, Y, HID, HID, EB);
  atb_kernel<<<64, 256, 0, stream>>>(X, Y, T);   // Rayleigh-Ritz matrix
  jacobi_kernel<<<1, 256, 0, stream>>>(T, Ucm, sel);
  vmat_kernel<<<64, 256, 0, stream>>>(X, Ucm, sel, V);
  loc_kernel<<<1250, 256, 0, stream>>>(h, V, loc);
  sq_kernel<<<40, 256, 0, stream>>>(loc, sq);
  knn_kernel<<<625, 256, 0, stream>>>(loc, sq, knn);

  // ---- layer 1 main path
  const float* w3_1   = w3 + (size_t)HID * HID;
  const float* b3_1   = b3 + HID;
  const float* wsrc_1 = v2_wsrc + (size_t)HID * HID;
  const float* bsrc_1 = v2_bsrc + HID;
  const float* wdst_1 = v2_wdst + (size_t)HID * HID;
  const float* bdst_1 = v2_bdst + HID;
  const float* attn_1 = v2_attn + HID;
  const float* gatw_1 = gat_w + (size_t)HID * HID;
  const float* al_1   = gat_al + HID;
  const float* ar_1   = gat_ar + HID;
  const float* gbias_1= gat_bias + HID;
  const float* gw_1   = gate_w + (size_t)HID * 2;
  const float* gb_1   = gate_b + 2;

  gemm_kernel<<<gemm_grid, 256, 0, stream>>>(h, w3_1, b3_1, h0b, N_NODES, HID, HID, 0);
  gemm_kernel<<<gemm_grid, 256, 0, stream>>>(h, wsrc_1, bsrc_1, fsb, N_NODES, HID, HID, 0);
  gemm_kernel<<<gemm_grid, 256, 0, stream>>>(h, wdst_1, bdst_1, fdb, N_NODES, HID, HID, 0);
  gatv2_kernel<<<N_NODES, 256, 0, stream>>>(fsb, fdb, src_idx, attn_1, h1b);
  // GATConv projection f reuses fsb (gatv2 done with it)
  gemm_kernel<<<gemm_grid, 256, 0, stream>>>(h, gatw_1, (const float*)nullptr, fsb, N_NODES, HID, HID, 0);
  elr_kernel<<<N_NODES, 256, 0, stream>>>(fsb, al_1, ar_1, el, er);
  gat_agg_kernel<<<N_NODES, 256, 0, stream>>>(fsb, knn, el, er, gbias_1, h2b);
  gate_kernel<<<N_NODES, 256, 0, stream>>>(h0b, gw_1, gb_1, theta);
  combine1_kernel<<<(int)((NE + 255) / 256), 256, 0, stream>>>(h0b, h1b, h2b, theta, out);
}